// Round 19
// baseline (277.845 us; speedup 1.0000x reference)
//
#include <hip/hip_runtime.h>
#include <cstdint>
#include <cstddef>

#define B_   4
#define C_   512
#define N_   4096
#define BN_EPS 1e-5f

typedef __attribute__((ext_vector_type(8))) short short8;
typedef __attribute__((ext_vector_type(8))) unsigned short ushort8;
typedef __attribute__((ext_vector_type(4))) unsigned short us4_t;
typedef __attribute__((ext_vector_type(4))) float f32x4;
typedef __attribute__((ext_vector_type(2))) unsigned uint2v;

__device__ __forceinline__ unsigned short f2b(float f) {
  union { float f; unsigned u; } v; v.f = f;
  unsigned u = v.u;
  return (unsigned short)((u + 0x7fffu + ((u >> 16) & 1u)) >> 16);
}
__device__ __forceinline__ float b2f(unsigned short h) {
  union { unsigned u; float f; } v; v.u = ((unsigned)h) << 16;
  return v.f;
}
__device__ __forceinline__ void async16(const void* g, void* l) {
  __builtin_amdgcn_global_load_lds((const __attribute__((address_space(1))) void*)g,
                                   (__attribute__((address_space(3))) void*)l, 16, 0, 0);
}

// ---------------- conversion kernel (x + weights, one launch) ----------------

__global__ __launch_bounds__(256) void convert_x_k(const float* __restrict__ x,
                                                   unsigned short* __restrict__ xcn,
                                                   unsigned short* __restrict__ xnc,
                                                   const float* __restrict__ wq,
                                                   const float* __restrict__ wk,
                                                   const float* __restrict__ wv,
                                                   const float* __restrict__ wf,
                                                   unsigned short* __restrict__ wqk,
                                                   unsigned short* __restrict__ wvb,
                                                   unsigned short* __restrict__ wfb) {
  __shared__ float tile[64][65];
  int bz = blockIdx.z;
  if (bz == 4) {
    int lin = (blockIdx.y * 8 + blockIdx.x) * 256 + threadIdx.x;
    wvb[lin] = f2b(wv[lin]);  wvb[lin + 131072] = f2b(wv[lin + 131072]);
    wfb[lin] = f2b(wf[lin]);  wfb[lin + 131072] = f2b(wf[lin + 131072]);
    if (lin < 65536) {
      int row = lin >> 9, col = lin & 511;
      float v = (row < 64) ? wq[row * 512 + col] : wk[(row - 64) * 512 + col];
      wqk[lin] = f2b(v);
    }
    return;
  }
  int c0 = blockIdx.x * 64, n0 = blockIdx.y * 64, b = bz;
  const float* xb = x + ((size_t)b * C_ + c0) * N_ + n0;
  unsigned short* cn = xcn + ((size_t)b * C_ + c0) * N_ + n0;
#pragma unroll
  for (int j = 0; j < 16; ++j) {
    int lin = j * 256 + threadIdx.x;
    int rr = lin >> 6, cc = lin & 63;
    float v = xb[(size_t)rr * N_ + cc];
    cn[(size_t)rr * N_ + cc] = f2b(v);
    tile[cc][rr] = v;
  }
  __syncthreads();
  unsigned short* nc = xnc + ((size_t)b * N_ + n0) * C_ + c0;
#pragma unroll
  for (int j = 0; j < 16; ++j) {
    int lin = j * 256 + threadIdx.x;
    int rr = lin >> 6, cc = lin & 63;
    nc[(size_t)rr * C_ + cc] = f2b(tile[rr][cc]);
  }
}

// ---------------- generic MFMA GEMM core ----------------

enum { EPI_BF16 = 0, EPI_F32 = 1, EPI_YB = 2 };

template<int EPI, bool SPLITK>
__device__ __forceinline__ void gemm_core(
    const unsigned short* __restrict__ A, size_t lda, size_t sA,
    const unsigned short* __restrict__ Bm, size_t ldb, size_t sB,
    void* __restrict__ Cv, size_t ldc, size_t sCbytes, int K,
    float* __restrict__ part, int bx, int by, int bz,
    unsigned short* lsA, unsigned short* lsB) {
  const int m0 = bx * 128, n0 = by * 128;
  char* Cb;
  if (SPLITK) {
    int bidx = bz & 3, ch = bz >> 2;
    A  += (size_t)bidx * sA + (size_t)ch * (size_t)K;
    Bm += (size_t)bidx * sB + (size_t)ch * (size_t)K;
    Cb = (char*)Cv + (size_t)bidx * sCbytes + (size_t)ch * 4u * sCbytes;
  } else {
    A  += (size_t)bz * sA;
    Bm += (size_t)bz * sB;
    Cb = (char*)Cv + (size_t)bz * sCbytes;
  }
  const int tid = threadIdx.x, lane = tid & 63, w = tid >> 6;
  const int wm = (w >> 1) * 64, wn = (w & 1) * 64;
  const int fr = lane & 15, fk = (lane >> 4) * 8;
  f32x4 acc[4][4];
#pragma unroll
  for (int i = 0; i < 4; ++i)
#pragma unroll
    for (int j = 0; j < 4; ++j) acc[i][j] = (f32x4){0.f, 0.f, 0.f, 0.f};

  const int i0 = tid, i1 = tid + 256;
  for (int k0 = 0; k0 < K; k0 += 32) {
    async16(A  + (size_t)(m0 + (i0 >> 2)) * lda + k0 + (i0 & 3) * 8, (char*)lsA + i0 * 16);
    async16(A  + (size_t)(m0 + (i1 >> 2)) * lda + k0 + (i1 & 3) * 8, (char*)lsA + i1 * 16);
    async16(Bm + (size_t)(n0 + (i0 >> 2)) * ldb + k0 + (i0 & 3) * 8, (char*)lsB + i0 * 16);
    async16(Bm + (size_t)(n0 + (i1 >> 2)) * ldb + k0 + (i1 & 3) * 8, (char*)lsB + i1 * 16);
    __syncthreads();
    short8 af[4], bfr[4];
#pragma unroll
    for (int mi = 0; mi < 4; ++mi)
      af[mi] = *(const short8*)&lsA[(wm + mi * 16 + fr) * 32 + fk];
#pragma unroll
    for (int ni = 0; ni < 4; ++ni)
      bfr[ni] = *(const short8*)&lsB[(wn + ni * 16 + fr) * 32 + fk];
#pragma unroll
    for (int mi = 0; mi < 4; ++mi)
#pragma unroll
      for (int ni = 0; ni < 4; ++ni)
        acc[mi][ni] = __builtin_amdgcn_mfma_f32_16x16x32_bf16(af[mi], bfr[ni], acc[mi][ni], 0, 0, 0);
    __syncthreads();
  }
  float cs[4] = {0.f, 0.f, 0.f, 0.f}, cq[4] = {0.f, 0.f, 0.f, 0.f};
#pragma unroll
  for (int mi = 0; mi < 4; ++mi)
#pragma unroll
    for (int ni = 0; ni < 4; ++ni)
#pragma unroll
      for (int r = 0; r < 4; ++r) {
        int gr = m0 + wm + mi * 16 + (lane >> 4) * 4 + r;
        int gc = n0 + wn + ni * 16 + fr;
        float v = acc[mi][ni][r];
        if (EPI == EPI_F32) ((float*)Cb)[(size_t)gr * ldc + gc] = v;
        else                ((unsigned short*)Cb)[(size_t)gr * ldc + gc] = f2b(v);
        if (EPI == EPI_YB) { cs[ni] += v; cq[ni] += v * v; }
      }
  if (EPI == EPI_YB) {
#pragma unroll
    for (int ni = 0; ni < 4; ++ni) {
      cs[ni] += __shfl_xor(cs[ni], 16, 64); cs[ni] += __shfl_xor(cs[ni], 32, 64);
      cq[ni] += __shfl_xor(cq[ni], 16, 64); cq[ni] += __shfl_xor(cq[ni], 32, 64);
    }
    float* fb = (float*)lsA;
    if (lane < 16) {
#pragma unroll
      for (int ni = 0; ni < 4; ++ni) {
        int col = wn + ni * 16 + lane;
        fb[((w >> 1) * 128 + col) * 2]     = cs[ni];
        fb[((w >> 1) * 128 + col) * 2 + 1] = cq[ni];
      }
    }
    __syncthreads();
    if (tid < 128) {
      float s = fb[tid * 2] + fb[(128 + tid) * 2];
      float q = fb[tid * 2 + 1] + fb[(128 + tid) * 2 + 1];
      int rg = bz * 32 + bx;
      int gcol = by * 128 + tid;
      part[(size_t)rg * 1024 + gcol * 2]     = s;
      part[(size_t)rg * 1024 + gcol * 2 + 1] = q;
    }
  }
}

template<int EPI, bool SPLITK = false>
__global__ __launch_bounds__(256)
void gemm_bt(const unsigned short* __restrict__ A, size_t lda, size_t sA,
             const unsigned short* __restrict__ Bm, size_t ldb, size_t sB,
             void* __restrict__ Cv, size_t ldc, size_t sCbytes, int K,
             float* __restrict__ part) {
  __shared__ unsigned short lsA[128 * 32];
  __shared__ unsigned short lsB[128 * 32];
  gemm_core<EPI, SPLITK>(A, lda, sA, Bm, ldb, sB, Cv, ldc, sCbytes, K, part,
                         blockIdx.x, blockIdx.y, blockIdx.z, lsA, lsB);
}

// Merged independent GEMMs: ce (split-K, longest -> first), qkT, v. 896 blocks.
__global__ __launch_bounds__(256)
void gemm3_k(const unsigned short* __restrict__ xnc, const unsigned short* __restrict__ xcn,
             const unsigned short* __restrict__ wqkb, const unsigned short* __restrict__ wvb,
             unsigned short* __restrict__ qkT, unsigned short* __restrict__ vmat,
             float* __restrict__ cepart) {
  __shared__ unsigned short lsA[128 * 32];
  __shared__ unsigned short lsB[128 * 32];
  int id = blockIdx.x;
  if (id < 256) {
    gemm_core<EPI_F32, true>(xcn, N_, (size_t)C_ * N_, xcn, N_, (size_t)C_ * N_,
                             cepart, 512, (size_t)512 * 512 * 4, 1024, nullptr,
                             id & 3, (id >> 2) & 3, id >> 4, lsA, lsB);
  } else if (id < 384) {
    int t = id - 256;
    gemm_core<EPI_BF16, false>(xnc, 512, (size_t)N_ * C_, wqkb, 512, 0,
                               qkT, 128, (size_t)N_ * 128 * 2, 512, nullptr,
                               t & 31, 0, t >> 5, lsA, lsB);
  } else {
    int t = id - 384;
    gemm_core<EPI_BF16, false>(wvb, 512, 0, xnc, 512, (size_t)N_ * C_,
                               vmat, N_, (size_t)C_ * N_ * 2, 512, nullptr,
                               t & 3, (t >> 2) & 31, t >> 7, lsA, lsB);
  }
}

// ---------------- fused position attention (2 blocks/CU: CC=128, KT=64) ----------------
// Halved block: 128 Q-rows x 128 out-cols, KT=64 (64 iters). LDS 66.5KB -> 2 blocks/CU
// (occupancy 21% -> ~42%): co-resident block hides the 2 barriers/iter (m114 overlap).
// Same verified phase logic with halved extents; P/V/K rows are 128B = 8 granules,
// swizzle g ^ (row&7) unchanged. Q all-register (bqr), cvt_pk P-pack.
// Spill tripwire: VGPR <= 128, WRITE_SIZE ~16.8MB.
#define QR 128
#define CC 128
#define KT 64
#define NIT (N_ / KT)

__global__ __launch_bounds__(512, 2)
void fused_pa_k(const unsigned short* __restrict__ qkT,   // [B][N][128] (q|k)
                const unsigned short* __restrict__ vmat,  // [B][C][N]
                const unsigned short* __restrict__ caT,   // [B][N][C]
                const unsigned short* __restrict__ xnc,   // [B][N][C]
                const float* __restrict__ gpa_p, const float* __restrict__ gca_p,
                unsigned short* __restrict__ sT) {        // [B][N][C]
  __shared__ unsigned short lsQ[QR * 64];     // 16KB
  __shared__ unsigned short lsK[2][KT * 64];  // 2x8KB
  __shared__ unsigned short lsV[CC * KT];     // 16KB
  __shared__ unsigned short lsP[QR * KT];     // 16KB
  __shared__ float lsL[8][64];
  __shared__ float invL[QR];

  const int bid = blockIdx.x;
  const int combo7 = bid & 7;                // b*2+chalf -> same XCD shares V-half + qkT batch
  const int b = combo7 >> 1, ch2 = combo7 & 1;
  const int cq = (bid >> 3) & 1;             // quarter within the half
  const int qt = bid >> 4;
  const int n0 = qt * QR, c0 = ch2 * 256 + cq * 128;

  const int tid = threadIdx.x, lane = tid & 63, w = tid >> 6;
  const int fr = lane & 15, fq = lane >> 4;  // fragment row / k-quarter
  const int wr = w >> 2, wc = w & 3;         // PV wave out-tile 64n x 32c
  const int ms = (w & 3) * 16;               // E-phase m-slice (16 rows)
  const int nb = (w >> 2) * 64;              // E-phase n-half (64 cols)

  const unsigned short* qk_b = qkT + (size_t)b * N_ * 128;
  const unsigned short* v_b  = vmat + (size_t)b * C_ * N_;

  f32x4 acc[4][2];
#pragma unroll
  for (int i = 0; i < 4; ++i)
#pragma unroll
    for (int j = 0; j < 2; ++j) acc[i][j] = (f32x4){0.f, 0.f, 0.f, 0.f};
  float lsum[4] = {0.f, 0.f, 0.f, 0.f};

  // stage Q (2/thread) and K[0] (1/thread)
#pragma unroll
  for (int j = 0; j < 2; ++j) {
    int idx = j * 512 + tid;
    int r = idx >> 3, g = idx & 7;
    async16(qk_b + (size_t)(n0 + r) * 128 + ((g ^ (r & 7)) << 3), (char*)lsQ + idx * 16);
  }
  {
    int r = tid >> 3, g = tid & 7;
    async16(qk_b + (size_t)r * 128 + 64 + ((g ^ (r & 7)) << 3), (char*)lsK[0] + tid * 16);
  }
  __syncthreads();

  // hoist ALL Q-fragments to registers (lsQ constant for the whole kernel)
  short8 bqr[4][2];
#pragma unroll
  for (int f = 0; f < 4; ++f) {
    int n = nb + f * 16 + fr;
    bqr[f][0] = *(const short8*)&lsQ[n * 64 + ((fq ^ (fr & 7)) << 3)];
    bqr[f][1] = *(const short8*)&lsQ[n * 64 + (((4 + fq) ^ (fr & 7)) << 3)];
  }

  for (int it = 0; it < NIT; ++it) {
    const int m0 = it * KT;
    // stage V[it] (2/thread)
#pragma unroll
    for (int j = 0; j < 2; ++j) {
      int idx = j * 512 + tid;
      int c = idx >> 3, g = idx & 7;
      async16(v_b + (size_t)(c0 + c) * N_ + m0 + ((g ^ (c & 7)) << 3), (char*)lsV + idx * 16);
    }
    // stage K[it+1] (1/thread)
    if (it < NIT - 1) {
      unsigned short* dst = lsK[(it + 1) & 1];
      int r = tid >> 3, g = tid & 7;
      async16(qk_b + (size_t)(m0 + KT + r) * 128 + 64 + ((g ^ (r & 7)) << 3),
              (char*)dst + tid * 16);
    }
    // E^T = K . Q^T over k=64; wave owns 16m x 64n (Q all-register)
    const unsigned short* lk = lsK[it & 1];
    short8 afk[2];
#pragma unroll
    for (int kk = 0; kk < 2; ++kk)
      afk[kk] = *(const short8*)&lk[(ms + fr) * 64 + (((kk * 4 + fq) ^ (fr & 7)) << 3)];
#pragma unroll
    for (int f = 0; f < 4; ++f) {
      int n = nb + f * 16 + fr;                // P row
      f32x4 e = (f32x4){0.f, 0.f, 0.f, 0.f};
      e = __builtin_amdgcn_mfma_f32_16x16x32_bf16(afk[0], bqr[f][0], e, 0, 0, 0);
      e = __builtin_amdgcn_mfma_f32_16x16x32_bf16(afk[1], bqr[f][1], e, 0, 0, 0);
      float p0 = __expf(e[0]), p1 = __expf(e[1]), p2 = __expf(e[2]), p3 = __expf(e[3]);
      float part = (p0 + p1) + (p2 + p3);
      int mb = ms + fq * 4;                    // 4 consecutive m in [0,64)
      unsigned w0, w1;
      asm("v_cvt_pk_bf16_f32 %0, %1, %2" : "=v"(w0) : "v"(p0), "v"(p1));
      asm("v_cvt_pk_bf16_f32 %0, %1, %2" : "=v"(w1) : "v"(p2), "v"(p3));
      uint2v pk; pk.x = w0; pk.y = w1;
      *(uint2v*)((char*)lsP + n * 128 + ((((mb >> 3) ^ (n & 7)) << 3) + (mb & 7)) * 2) = pk;
      part += __shfl_xor(part, 16, 64);
      part += __shfl_xor(part, 32, 64);
      lsum[f] += part;
    }
    __syncthreads();   // P visible; V (and next K) landed
    // PV: out[n][c] += P[n][m] * V[c][m]; wave tile 64n x 32c, K=64 in 2 chunks
#pragma unroll
    for (int kk4 = 0; kk4 < 2; ++kk4) {
      short8 pa[4], vbf[2];
#pragma unroll
      for (int mi = 0; mi < 4; ++mi) {
        int n = wr * 64 + mi * 16 + fr;
        pa[mi] = *(const short8*)((const char*)lsP + n * 128 + (((kk4 * 4 + fq) ^ (n & 7)) << 4));
      }
#pragma unroll
      for (int ni = 0; ni < 2; ++ni) {
        int c = wc * 32 + ni * 16 + fr;
        vbf[ni] = *(const short8*)((const char*)lsV + c * 128 + (((kk4 * 4 + fq) ^ (c & 7)) << 4));
      }
#pragma unroll
      for (int mi = 0; mi < 4; ++mi)
#pragma unroll
        for (int ni = 0; ni < 2; ++ni)
          acc[mi][ni] = __builtin_amdgcn_mfma_f32_16x16x32_bf16(pa[mi], vbf[ni], acc[mi][ni], 0, 0, 0);
    }
    __syncthreads();   // all reads of lsP/lsV done before next stage/overwrite
  }

  // reduce rowsums: row n = nh*64 + j summed over 4 m-slice waves (w = nh*4 + ma)
  if (lane < 16) {
#pragma unroll
    for (int f = 0; f < 4; ++f) lsL[w][f * 16 + lane] = lsum[f];
  }
  __syncthreads();
  if (tid < QR) {
    int nh = tid >> 6, j = tid & 63;
    invL[tid] = 1.f / (lsL[4 * nh][j] + lsL[4 * nh + 1][j] + lsL[4 * nh + 2][j] + lsL[4 * nh + 3][j]);
  }
  __syncthreads();

  const float gpa = gpa_p[0], gca = gca_p[0];
#pragma unroll
  for (int mi = 0; mi < 4; ++mi)
#pragma unroll
    for (int ni = 0; ni < 2; ++ni)
#pragma unroll
      for (int r = 0; r < 4; ++r) {
        int nl = wr * 64 + mi * 16 + fq * 4 + r;
        int gn = n0 + nl;
        int gc = c0 + wc * 32 + ni * 16 + fr;
        size_t eo = ((size_t)b * N_ + gn) * C_ + gc;
        float sv = gpa * acc[mi][ni][r] * invL[nl] + gca * b2f(caT[eo]) + 2.f * b2f(xnc[eo]);
        sT[eo] = f2b(sv);
      }
}

// ---------------- channel-attention softmax over ce partials ----------------
__global__ __launch_bounds__(256) void ce_softmax_k(const float* __restrict__ cepart,
                                                    unsigned short* __restrict__ cattn) {
  int wid = threadIdx.x >> 6, lane = threadIdx.x & 63;
  size_t row = (size_t)blockIdx.x * 4 + wid;
  float v[8]; float mn = 3.4e38f;
#pragma unroll
  for (int i = 0; i < 8; ++i) {
    size_t idx = row * C_ + (size_t)(i * 64 + lane);
    float t = cepart[idx] + cepart[idx + 1048576] + cepart[idx + 2097152] + cepart[idx + 3145728];
    v[i] = t; mn = fminf(mn, t);
  }
#pragma unroll
  for (int o = 1; o < 64; o <<= 1) mn = fminf(mn, __shfl_xor(mn, o, 64));
  float s = 0.f, p[8];
#pragma unroll
  for (int i = 0; i < 8; ++i) { p[i] = expf(mn - v[i]); s += p[i]; }
#pragma unroll
  for (int o = 1; o < 64; o <<= 1) s += __shfl_xor(s, o, 64);
  float inv = 1.f / s;
  unsigned short* orow = cattn + row * C_;
#pragma unroll
  for (int i = 0; i < 8; ++i) orow[i * 64 + lane] = f2b(p[i] * inv);
}

// ---------------- BN finalize (inline, redundant per block) + apply + transpose + relu ----
__global__ __launch_bounds__(256) void bn_apply_k(const unsigned short* __restrict__ yT,
                                                  const float* __restrict__ part,
                                                  const float* __restrict__ bns,
                                                  const float* __restrict__ bnb,
                                                  float* __restrict__ out) {
  __shared__ float tile[64][65];
  __shared__ float red[4][64][2];
  __shared__ float abv[64][2];
  int n0 = blockIdx.x * 64, o0 = blockIdx.y * 64, b = blockIdx.z;
  int t = threadIdx.x;
  {
    int col = o0 + (t & 63), seg = t >> 6;
    float s = 0.f, q = 0.f;
    for (int p = seg * 32; p < seg * 32 + 32; ++p) {
      s += part[(size_t)p * 1024 + col * 2];
      q += part[(size_t)p * 1024 + col * 2 + 1];
    }
    red[seg][t & 63][0] = s; red[seg][t & 63][1] = q;
  }
  __syncthreads();
  if (t < 64) {
    float S = red[0][t][0] + red[1][t][0] + red[2][t][0] + red[3][t][0];
    float Q = red[0][t][1] + red[1][t][1] + red[2][t][1] + red[3][t][1];
    float mean = S * (1.f / 16384.f);
    float var  = Q * (1.f / 16384.f) - mean * mean;
    float istd = rsqrtf(var + BN_EPS);
    float a = bns[o0 + t] * istd;
    abv[t][0] = a;
    abv[t][1] = bnb[o0 + t] - mean * a;
  }
  __syncthreads();
  const unsigned short* yb = yT + ((size_t)b * N_ + n0) * C_ + o0;
#pragma unroll
  for (int j = 0; j < 16; ++j) {
    int lin = j * 256 + t;
    int rr = lin >> 6, cc = lin & 63;
    float v = b2f(yb[(size_t)rr * C_ + cc]);
    tile[cc][rr] = fmaxf(v * abv[cc][0] + abv[cc][1], 0.f);
  }
  __syncthreads();
  float* ob = out + ((size_t)b * C_ + o0) * N_ + n0;
#pragma unroll
  for (int j = 0; j < 16; ++j) {
    int lin = j * 256 + t;
    int rr = lin >> 6, cc = lin & 63;
    ob[(size_t)rr * N_ + cc] = tile[rr][cc];
  }
}

// ---------------- host launch ----------------

extern "C" void kernel_launch(void* const* d_in, const int* in_sizes, int n_in,
                              void* d_out, int out_size, void* d_ws, size_t ws_size,
                              hipStream_t stream) {
  (void)in_sizes; (void)n_in; (void)out_size; (void)ws_size;
  const float* x   = (const float*)d_in[0];
  const float* wq  = (const float*)d_in[1];
  const float* wk  = (const float*)d_in[2];
  const float* wv  = (const float*)d_in[3];
  const float* wf  = (const float*)d_in[4];
  const float* gpa = (const float*)d_in[5];
  const float* gca = (const float*)d_in[6];
  const float* bns = (const float*)d_in[7];
  const float* bnb = (const float*)d_in[8];
  float* out = (float*)d_out;

  char* ws = (char*)d_ws;
  size_t off = 0;
  auto carve = [&](size_t bytes) -> char* {
    off = (off + 255) & ~(size_t)255;
    char* p = ws + off; off += bytes; return p;
  };

  unsigned short* xcn   = (unsigned short*)carve((size_t)B_ * C_ * N_ * 2);  // reused as sT
  unsigned short* xnc   = (unsigned short*)carve((size_t)B_ * C_ * N_ * 2);
  unsigned short* wqkb  = (unsigned short*)carve(128 * 512 * 2);
  unsigned short* wvb   = (unsigned short*)carve(512 * 512 * 2);
  unsigned short* wfb   = (unsigned short*)carve(512 * 512 * 2);
  unsigned short* qkT   = (unsigned short*)carve((size_t)B_ * N_ * 128 * 2);
  unsigned short* vmat  = (unsigned short*)carve((size_t)B_ * C_ * N_ * 2);
  float*          cepart= (float*)carve((size_t)4 * B_ * 512 * 512 * 4);     // reused as yT (bf16)
  unsigned short* cattn = (unsigned short*)carve((size_t)B_ * 512 * 512 * 2);
  unsigned short* caT   = (unsigned short*)carve((size_t)B_ * N_ * C_ * 2);
  float*          bnpart= (float*)carve((size_t)128 * 1024 * 4);

  unsigned short* yT = (unsigned short*)cepart;  // overlay: cepart dead after ce_softmax
  unsigned short* sT = xcn;                      // overlay: xcn dead after ce GEMM

  // 1) conversions (x + weights in one launch)
  convert_x_k<<<dim3(C_ / 64, N_ / 64, 5), 256, 0, stream>>>(
      x, xcn, xnc, wq, wk, wv, wf, wqkb, wvb, wfb);

  // 2) merged independent GEMMs: ce (split-K, first), qkT, v — 896 blocks
  gemm3_k<<<dim3(896), 256, 0, stream>>>(xnc, xcn, wqkb, wvb, qkT, vmat, cepart);

  // 3) channel softmax -> cattn bf16
  ce_softmax_k<<<dim3(B_ * 512 / 4), 256, 0, stream>>>(cepart, cattn);

  // 4) caT[n][c] = xnc @ cattn^T
  gemm_bt<EPI_BF16><<<dim3(32, 4, 4), 256, 0, stream>>>(
      xnc, 512, (size_t)N_ * C_, cattn, 512, (size_t)512 * 512,
      caT, 512, (size_t)N_ * C_ * 2, 512, nullptr);

  // 5) fused position attention + combine epilogue -> sT (512 blocks, 2/CU)
  fused_pa_k<<<dim3(512), 512, 0, stream>>>(qkT, vmat, caT, xnc, gpa, gca, sT);

  // 6) yT[n][o] = sT @ wfuse^T (bf16) with fused per-block BN column partials
  gemm_bt<EPI_YB><<<dim3(32, 4, 4), 256, 0, stream>>>(
      sT, 512, (size_t)N_ * C_, wfb, 512, 0,
      yT, 512, (size_t)N_ * C_ * 2, 512, bnpart);

  // 7) BN finalize (inline) + apply + transpose + relu
  bn_apply_k<<<dim3(N_ / 64, C_ / 64, B_), 256, 0, stream>>>(yT, bnpart, bns, bnb, out);
}

// Round 20
// 207.970 us; speedup vs baseline: 1.3360x; 1.3360x over previous
//
#include <hip/hip_runtime.h>
#include <cstdint>
#include <cstddef>

#define B_   4
#define C_   512
#define N_   4096
#define BN_EPS 1e-5f

typedef __attribute__((ext_vector_type(8))) short short8;
typedef __attribute__((ext_vector_type(8))) unsigned short ushort8;
typedef __attribute__((ext_vector_type(4))) unsigned short us4_t;
typedef __attribute__((ext_vector_type(4))) float f32x4;
typedef __attribute__((ext_vector_type(2))) unsigned uint2v;

__device__ __forceinline__ unsigned short f2b(float f) {
  union { float f; unsigned u; } v; v.f = f;
  unsigned u = v.u;
  return (unsigned short)((u + 0x7fffu + ((u >> 16) & 1u)) >> 16);
}
__device__ __forceinline__ float b2f(unsigned short h) {
  union { unsigned u; float f; } v; v.u = ((unsigned)h) << 16;
  return v.f;
}
__device__ __forceinline__ void async16(const void* g, void* l) {
  __builtin_amdgcn_global_load_lds((const __attribute__((address_space(1))) void*)g,
                                   (__attribute__((address_space(3))) void*)l, 16, 0, 0);
}

// ---------------- conversion kernel (x + weights, one launch) ----------------

__global__ __launch_bounds__(256) void convert_x_k(const float* __restrict__ x,
                                                   unsigned short* __restrict__ xcn,
                                                   unsigned short* __restrict__ xnc,
                                                   const float* __restrict__ wq,
                                                   const float* __restrict__ wk,
                                                   const float* __restrict__ wv,
                                                   const float* __restrict__ wf,
                                                   unsigned short* __restrict__ wqk,
                                                   unsigned short* __restrict__ wvb,
                                                   unsigned short* __restrict__ wfb) {
  __shared__ float tile[64][65];
  int bz = blockIdx.z;
  if (bz == 4) {
    int lin = (blockIdx.y * 8 + blockIdx.x) * 256 + threadIdx.x;
    wvb[lin] = f2b(wv[lin]);  wvb[lin + 131072] = f2b(wv[lin + 131072]);
    wfb[lin] = f2b(wf[lin]);  wfb[lin + 131072] = f2b(wf[lin + 131072]);
    if (lin < 65536) {
      int row = lin >> 9, col = lin & 511;
      float v = (row < 64) ? wq[row * 512 + col] : wk[(row - 64) * 512 + col];
      wqk[lin] = f2b(v);
    }
    return;
  }
  int c0 = blockIdx.x * 64, n0 = blockIdx.y * 64, b = bz;
  const float* xb = x + ((size_t)b * C_ + c0) * N_ + n0;
  unsigned short* cn = xcn + ((size_t)b * C_ + c0) * N_ + n0;
#pragma unroll
  for (int j = 0; j < 16; ++j) {
    int lin = j * 256 + threadIdx.x;
    int rr = lin >> 6, cc = lin & 63;
    float v = xb[(size_t)rr * N_ + cc];
    cn[(size_t)rr * N_ + cc] = f2b(v);
    tile[cc][rr] = v;
  }
  __syncthreads();
  unsigned short* nc = xnc + ((size_t)b * N_ + n0) * C_ + c0;
#pragma unroll
  for (int j = 0; j < 16; ++j) {
    int lin = j * 256 + threadIdx.x;
    int rr = lin >> 6, cc = lin & 63;
    nc[(size_t)rr * C_ + cc] = f2b(tile[rr][cc]);
  }
}

// ---------------- generic MFMA GEMM core ----------------

enum { EPI_BF16 = 0, EPI_F32 = 1, EPI_YB = 2 };

template<int EPI, bool SPLITK>
__device__ __forceinline__ void gemm_core(
    const unsigned short* __restrict__ A, size_t lda, size_t sA,
    const unsigned short* __restrict__ Bm, size_t ldb, size_t sB,
    void* __restrict__ Cv, size_t ldc, size_t sCbytes, int K,
    float* __restrict__ part, int bx, int by, int bz,
    unsigned short* lsA, unsigned short* lsB) {
  const int m0 = bx * 128, n0 = by * 128;
  char* Cb;
  if (SPLITK) {
    int bidx = bz & 3, ch = bz >> 2;
    A  += (size_t)bidx * sA + (size_t)ch * (size_t)K;
    Bm += (size_t)bidx * sB + (size_t)ch * (size_t)K;
    Cb = (char*)Cv + (size_t)bidx * sCbytes + (size_t)ch * 4u * sCbytes;
  } else {
    A  += (size_t)bz * sA;
    Bm += (size_t)bz * sB;
    Cb = (char*)Cv + (size_t)bz * sCbytes;
  }
  const int tid = threadIdx.x, lane = tid & 63, w = tid >> 6;
  const int wm = (w >> 1) * 64, wn = (w & 1) * 64;
  const int fr = lane & 15, fk = (lane >> 4) * 8;
  f32x4 acc[4][4];
#pragma unroll
  for (int i = 0; i < 4; ++i)
#pragma unroll
    for (int j = 0; j < 4; ++j) acc[i][j] = (f32x4){0.f, 0.f, 0.f, 0.f};

  const int i0 = tid, i1 = tid + 256;
  for (int k0 = 0; k0 < K; k0 += 32) {
    async16(A  + (size_t)(m0 + (i0 >> 2)) * lda + k0 + (i0 & 3) * 8, (char*)lsA + i0 * 16);
    async16(A  + (size_t)(m0 + (i1 >> 2)) * lda + k0 + (i1 & 3) * 8, (char*)lsA + i1 * 16);
    async16(Bm + (size_t)(n0 + (i0 >> 2)) * ldb + k0 + (i0 & 3) * 8, (char*)lsB + i0 * 16);
    async16(Bm + (size_t)(n0 + (i1 >> 2)) * ldb + k0 + (i1 & 3) * 8, (char*)lsB + i1 * 16);
    __syncthreads();
    short8 af[4], bfr[4];
#pragma unroll
    for (int mi = 0; mi < 4; ++mi)
      af[mi] = *(const short8*)&lsA[(wm + mi * 16 + fr) * 32 + fk];
#pragma unroll
    for (int ni = 0; ni < 4; ++ni)
      bfr[ni] = *(const short8*)&lsB[(wn + ni * 16 + fr) * 32 + fk];
#pragma unroll
    for (int mi = 0; mi < 4; ++mi)
#pragma unroll
      for (int ni = 0; ni < 4; ++ni)
        acc[mi][ni] = __builtin_amdgcn_mfma_f32_16x16x32_bf16(af[mi], bfr[ni], acc[mi][ni], 0, 0, 0);
    __syncthreads();
  }
  float cs[4] = {0.f, 0.f, 0.f, 0.f}, cq[4] = {0.f, 0.f, 0.f, 0.f};
#pragma unroll
  for (int mi = 0; mi < 4; ++mi)
#pragma unroll
    for (int ni = 0; ni < 4; ++ni)
#pragma unroll
      for (int r = 0; r < 4; ++r) {
        int gr = m0 + wm + mi * 16 + (lane >> 4) * 4 + r;
        int gc = n0 + wn + ni * 16 + fr;
        float v = acc[mi][ni][r];
        if (EPI == EPI_F32) ((float*)Cb)[(size_t)gr * ldc + gc] = v;
        else                ((unsigned short*)Cb)[(size_t)gr * ldc + gc] = f2b(v);
        if (EPI == EPI_YB) { cs[ni] += v; cq[ni] += v * v; }
      }
  if (EPI == EPI_YB) {
#pragma unroll
    for (int ni = 0; ni < 4; ++ni) {
      cs[ni] += __shfl_xor(cs[ni], 16, 64); cs[ni] += __shfl_xor(cs[ni], 32, 64);
      cq[ni] += __shfl_xor(cq[ni], 16, 64); cq[ni] += __shfl_xor(cq[ni], 32, 64);
    }
    float* fb = (float*)lsA;
    if (lane < 16) {
#pragma unroll
      for (int ni = 0; ni < 4; ++ni) {
        int col = wn + ni * 16 + lane;
        fb[((w >> 1) * 128 + col) * 2]     = cs[ni];
        fb[((w >> 1) * 128 + col) * 2 + 1] = cq[ni];
      }
    }
    __syncthreads();
    if (tid < 128) {
      float s = fb[tid * 2] + fb[(128 + tid) * 2];
      float q = fb[tid * 2 + 1] + fb[(128 + tid) * 2 + 1];
      int rg = bz * 32 + bx;
      int gcol = by * 128 + tid;
      part[(size_t)rg * 1024 + gcol * 2]     = s;
      part[(size_t)rg * 1024 + gcol * 2 + 1] = q;
    }
  }
}

template<int EPI, bool SPLITK = false>
__global__ __launch_bounds__(256)
void gemm_bt(const unsigned short* __restrict__ A, size_t lda, size_t sA,
             const unsigned short* __restrict__ Bm, size_t ldb, size_t sB,
             void* __restrict__ Cv, size_t ldc, size_t sCbytes, int K,
             float* __restrict__ part) {
  __shared__ unsigned short lsA[128 * 32];
  __shared__ unsigned short lsB[128 * 32];
  gemm_core<EPI, SPLITK>(A, lda, sA, Bm, ldb, sB, Cv, ldc, sCbytes, K, part,
                         blockIdx.x, blockIdx.y, blockIdx.z, lsA, lsB);
}

// Merged independent GEMMs: ce (split-K, longest -> first), qkT, v. 896 blocks.
__global__ __launch_bounds__(256)
void gemm3_k(const unsigned short* __restrict__ xnc, const unsigned short* __restrict__ xcn,
             const unsigned short* __restrict__ wqkb, const unsigned short* __restrict__ wvb,
             unsigned short* __restrict__ qkT, unsigned short* __restrict__ vmat,
             float* __restrict__ cepart) {
  __shared__ unsigned short lsA[128 * 32];
  __shared__ unsigned short lsB[128 * 32];
  int id = blockIdx.x;
  if (id < 256) {
    gemm_core<EPI_F32, true>(xcn, N_, (size_t)C_ * N_, xcn, N_, (size_t)C_ * N_,
                             cepart, 512, (size_t)512 * 512 * 4, 1024, nullptr,
                             id & 3, (id >> 2) & 3, id >> 4, lsA, lsB);
  } else if (id < 384) {
    int t = id - 256;
    gemm_core<EPI_BF16, false>(xnc, 512, (size_t)N_ * C_, wqkb, 512, 0,
                               qkT, 128, (size_t)N_ * 128 * 2, 512, nullptr,
                               t & 31, 0, t >> 5, lsA, lsB);
  } else {
    int t = id - 384;
    gemm_core<EPI_BF16, false>(wvb, 512, 0, xnc, 512, (size_t)N_ * C_,
                               vmat, N_, (size_t)C_ * N_ * 2, 512, nullptr,
                               t & 3, (t >> 2) & 31, t >> 7, lsA, lsB);
  }
}

// ---------------- fused position attention (R18 verified: converged structure) ----------
// per block: 128 Q-rows x 256 out-cols; K-tiles of 128 over m (32 iters).
// E-phase: wave = 32m x 64n; ALL Q-fragments in registers (bqr[4][2], 32 VGPR);
// K LDS-dbuf; V staged per iter; P swizzled LDS; cvt_pk P-pack.
// Structural alternatives all regressed: V-direct (R6), reg-K (R7-9,R13 spill/vmcnt),
// ca-tail fusion (R14), half-block 2/CU (R19: 4x E redundancy + 2x barriers).
#define QR 128
#define CC 256
#define KT 128

__global__ __launch_bounds__(512, 2)
void fused_pa_k(const unsigned short* __restrict__ qkT,   // [B][N][128] (q|k)
                const unsigned short* __restrict__ vmat,  // [B][C][N]
                const unsigned short* __restrict__ caT,   // [B][N][C]
                const unsigned short* __restrict__ xnc,   // [B][N][C]
                const float* __restrict__ gpa_p, const float* __restrict__ gca_p,
                unsigned short* __restrict__ sT) {        // [B][N][C]
  __shared__ unsigned short lsQ[QR * 64];
  __shared__ unsigned short lsK[2][KT * 64];
  __shared__ unsigned short lsV[CC * KT];
  __shared__ unsigned short lsP[QR * KT];
  __shared__ float lsL[8][64];
  __shared__ float invL[QR];

  const int bid = blockIdx.x;
  const int combo = bid & 7;                 // b*2+chalf -> same XCD shares V-half
  const int b = combo >> 1, chalf = combo & 1;
  const int qt = bid >> 3;
  const int n0 = qt * QR, c0 = chalf * CC;

  const int tid = threadIdx.x, lane = tid & 63, w = tid >> 6;
  const int fr = lane & 15, fq = lane >> 4;  // fragment row / k-quarter
  const int wr = w >> 2, wc = w & 3;         // PV wave out-tile 64x64
  const int ms = (w & 3) * 32;               // E-phase m-slice (32 rows)
  const int nb = (w >> 2) * 64;              // E-phase n-half (64 cols)

  const unsigned short* qk_b = qkT + (size_t)b * N_ * 128;
  const unsigned short* v_b  = vmat + (size_t)b * C_ * N_;

  f32x4 acc[4][4];
#pragma unroll
  for (int i = 0; i < 4; ++i)
#pragma unroll
    for (int j = 0; j < 4; ++j) acc[i][j] = (f32x4){0.f, 0.f, 0.f, 0.f};
  float lsum[4] = {0.f, 0.f, 0.f, 0.f};

  // stage Q (once) and K[0]
#pragma unroll
  for (int j = 0; j < 2; ++j) {
    int idx = j * 512 + tid;
    int r = idx >> 3, g = idx & 7;
    async16(qk_b + (size_t)(n0 + r) * 128 + ((g ^ (r & 7)) << 3), (char*)lsQ + idx * 16);
  }
#pragma unroll
  for (int j = 0; j < 2; ++j) {
    int idx = j * 512 + tid;
    int r = idx >> 3, g = idx & 7;
    async16(qk_b + (size_t)r * 128 + 64 + ((g ^ (r & 7)) << 3), (char*)lsK[0] + idx * 16);
  }
  __syncthreads();

  // hoist ALL Q-fragments to registers (lsQ constant for the whole kernel)
  short8 bqr[4][2];
#pragma unroll
  for (int f = 0; f < 4; ++f) {
    int n = nb + f * 16 + fr;
    bqr[f][0] = *(const short8*)&lsQ[n * 64 + ((fq ^ (fr & 7)) << 3)];
    bqr[f][1] = *(const short8*)&lsQ[n * 64 + (((4 + fq) ^ (fr & 7)) << 3)];
  }

  for (int it = 0; it < N_ / KT; ++it) {
    const int m0 = it * KT;
    // stage V[it]
#pragma unroll
    for (int j = 0; j < 8; ++j) {
      int idx = j * 512 + tid;
      int c = idx >> 4, g = idx & 15;
      async16(v_b + (size_t)(c0 + c) * N_ + m0 + ((g ^ (c & 7)) << 3), (char*)lsV + idx * 16);
    }
    // stage K[it+1]
    if (it < N_ / KT - 1) {
      unsigned short* dst = lsK[(it + 1) & 1];
#pragma unroll
      for (int j = 0; j < 2; ++j) {
        int idx = j * 512 + tid;
        int r = idx >> 3, g = idx & 7;
        async16(qk_b + (size_t)(m0 + KT + r) * 128 + 64 + ((g ^ (r & 7)) << 3),
                (char*)dst + idx * 16);
      }
    }
    // E^T = K . Q^T over k=64; wave owns 32m x 64n (Q all-register)
    const unsigned short* lk = lsK[it & 1];
    short8 afk[2][2];
#pragma unroll
    for (int mi = 0; mi < 2; ++mi)
#pragma unroll
      for (int kk = 0; kk < 2; ++kk)
        afk[mi][kk] = *(const short8*)&lk[(ms + mi * 16 + fr) * 64 + (((kk * 4 + fq) ^ (fr & 7)) << 3)];
#pragma unroll
    for (int f = 0; f < 4; ++f) {
      int n = nb + f * 16 + fr;                // P row
      float part = 0.f;
#pragma unroll
      for (int mi = 0; mi < 2; ++mi) {
        f32x4 e = (f32x4){0.f, 0.f, 0.f, 0.f};
        e = __builtin_amdgcn_mfma_f32_16x16x32_bf16(afk[mi][0], bqr[f][0], e, 0, 0, 0);
        e = __builtin_amdgcn_mfma_f32_16x16x32_bf16(afk[mi][1], bqr[f][1], e, 0, 0, 0);
        float p0 = __expf(e[0]), p1 = __expf(e[1]), p2 = __expf(e[2]), p3 = __expf(e[3]);
        part += (p0 + p1) + (p2 + p3);
        int mb = ms + mi * 16 + fq * 4;        // 4 consecutive m
        unsigned w0, w1;
        asm("v_cvt_pk_bf16_f32 %0, %1, %2" : "=v"(w0) : "v"(p0), "v"(p1));
        asm("v_cvt_pk_bf16_f32 %0, %1, %2" : "=v"(w1) : "v"(p2), "v"(p3));
        uint2v pk; pk.x = w0; pk.y = w1;
        *(uint2v*)((char*)lsP + n * 256 + ((((mb >> 3) ^ (n & 7)) << 3) + (mb & 7)) * 2) = pk;
      }
      part += __shfl_xor(part, 16, 64);
      part += __shfl_xor(part, 32, 64);
      lsum[f] += part;
    }
    __syncthreads();   // P visible; V (and next K) landed
    // PV: out[n][c] += P[n][m] * V[c][m]
#pragma unroll
    for (int kk4 = 0; kk4 < 4; ++kk4) {
      short8 pa[4], vbf[4];
#pragma unroll
      for (int mi = 0; mi < 4; ++mi) {
        int n = wr * 64 + mi * 16 + fr;
        pa[mi] = *(const short8*)((const char*)lsP + n * 256 + (((kk4 * 4 + fq) ^ (n & 7)) << 4));
      }
#pragma unroll
      for (int ni = 0; ni < 4; ++ni) {
        int c = wc * 64 + ni * 16 + fr;
        vbf[ni] = *(const short8*)((const char*)lsV + c * 256 + (((kk4 * 4 + fq) ^ (c & 7)) << 4));
      }
#pragma unroll
      for (int mi = 0; mi < 4; ++mi)
#pragma unroll
        for (int ni = 0; ni < 4; ++ni)
          acc[mi][ni] = __builtin_amdgcn_mfma_f32_16x16x32_bf16(pa[mi], vbf[ni], acc[mi][ni], 0, 0, 0);
    }
    __syncthreads();   // all reads of lsP/lsV done before next stage/overwrite
  }

  // reduce rowsums: row n = nh*64 + j summed over 4 m-slice waves (w = nh*4 + ma)
  if (lane < 16) {
#pragma unroll
    for (int f = 0; f < 4; ++f) lsL[w][f * 16 + lane] = lsum[f];
  }
  __syncthreads();
  if (tid < QR) {
    int nh = tid >> 6, j = tid & 63;
    invL[tid] = 1.f / (lsL[4 * nh][j] + lsL[4 * nh + 1][j] + lsL[4 * nh + 2][j] + lsL[4 * nh + 3][j]);
  }
  __syncthreads();

  const float gpa = gpa_p[0], gca = gca_p[0];
#pragma unroll
  for (int mi = 0; mi < 4; ++mi)
#pragma unroll
    for (int ni = 0; ni < 4; ++ni)
#pragma unroll
      for (int r = 0; r < 4; ++r) {
        int nl = wr * 64 + mi * 16 + fq * 4 + r;
        int gn = n0 + nl;
        int gc = c0 + wc * 64 + ni * 16 + fr;
        size_t eo = ((size_t)b * N_ + gn) * C_ + gc;
        float sv = gpa * acc[mi][ni][r] * invL[nl] + gca * b2f(caT[eo]) + 2.f * b2f(xnc[eo]);
        sT[eo] = f2b(sv);
      }
}

// ---------------- channel-attention softmax over ce partials ----------------
__global__ __launch_bounds__(256) void ce_softmax_k(const float* __restrict__ cepart,
                                                    unsigned short* __restrict__ cattn) {
  int wid = threadIdx.x >> 6, lane = threadIdx.x & 63;
  size_t row = (size_t)blockIdx.x * 4 + wid;
  float v[8]; float mn = 3.4e38f;
#pragma unroll
  for (int i = 0; i < 8; ++i) {
    size_t idx = row * C_ + (size_t)(i * 64 + lane);
    float t = cepart[idx] + cepart[idx + 1048576] + cepart[idx + 2097152] + cepart[idx + 3145728];
    v[i] = t; mn = fminf(mn, t);
  }
#pragma unroll
  for (int o = 1; o < 64; o <<= 1) mn = fminf(mn, __shfl_xor(mn, o, 64));
  float s = 0.f, p[8];
#pragma unroll
  for (int i = 0; i < 8; ++i) { p[i] = __expf(mn - v[i]); s += p[i]; }
#pragma unroll
  for (int o = 1; o < 64; o <<= 1) s += __shfl_xor(s, o, 64);
  float inv = 1.f / s;
  unsigned short* orow = cattn + row * C_;
#pragma unroll
  for (int i = 0; i < 8; ++i) orow[i * 64 + lane] = f2b(p[i] * inv);
}

// ---------------- BN finalize (inline, redundant per block) + apply + transpose + relu ----
__global__ __launch_bounds__(256) void bn_apply_k(const unsigned short* __restrict__ yT,
                                                  const float* __restrict__ part,
                                                  const float* __restrict__ bns,
                                                  const float* __restrict__ bnb,
                                                  float* __restrict__ out) {
  __shared__ float tile[64][65];
  __shared__ float red[4][64][2];
  __shared__ float abv[64][2];
  int n0 = blockIdx.x * 64, o0 = blockIdx.y * 64, b = blockIdx.z;
  int t = threadIdx.x;
  {
    int col = o0 + (t & 63), seg = t >> 6;
    float s = 0.f, q = 0.f;
    for (int p = seg * 32; p < seg * 32 + 32; ++p) {
      s += part[(size_t)p * 1024 + col * 2];
      q += part[(size_t)p * 1024 + col * 2 + 1];
    }
    red[seg][t & 63][0] = s; red[seg][t & 63][1] = q;
  }
  __syncthreads();
  if (t < 64) {
    float S = red[0][t][0] + red[1][t][0] + red[2][t][0] + red[3][t][0];
    float Q = red[0][t][1] + red[1][t][1] + red[2][t][1] + red[3][t][1];
    float mean = S * (1.f / 16384.f);
    float var  = Q * (1.f / 16384.f) - mean * mean;
    float istd = rsqrtf(var + BN_EPS);
    float a = bns[o0 + t] * istd;
    abv[t][0] = a;
    abv[t][1] = bnb[o0 + t] - mean * a;
  }
  __syncthreads();
  const unsigned short* yb = yT + ((size_t)b * N_ + n0) * C_ + o0;
#pragma unroll
  for (int j = 0; j < 16; ++j) {
    int lin = j * 256 + t;
    int rr = lin >> 6, cc = lin & 63;
    float v = b2f(yb[(size_t)rr * C_ + cc]);
    tile[cc][rr] = fmaxf(v * abv[cc][0] + abv[cc][1], 0.f);
  }
  __syncthreads();
  float* ob = out + ((size_t)b * C_ + o0) * N_ + n0;
#pragma unroll
  for (int j = 0; j < 16; ++j) {
    int lin = j * 256 + t;
    int rr = lin >> 6, cc = lin & 63;
    ob[(size_t)rr * N_ + cc] = tile[rr][cc];
  }
}

// ---------------- host launch ----------------

extern "C" void kernel_launch(void* const* d_in, const int* in_sizes, int n_in,
                              void* d_out, int out_size, void* d_ws, size_t ws_size,
                              hipStream_t stream) {
  (void)in_sizes; (void)n_in; (void)out_size; (void)ws_size;
  const float* x   = (const float*)d_in[0];
  const float* wq  = (const float*)d_in[1];
  const float* wk  = (const float*)d_in[2];
  const float* wv  = (const float*)d_in[3];
  const float* wf  = (const float*)d_in[4];
  const float* gpa = (const float*)d_in[5];
  const float* gca = (const float*)d_in[6];
  const float* bns = (const float*)d_in[7];
  const float* bnb = (const float*)d_in[8];
  float* out = (float*)d_out;

  char* ws = (char*)d_ws;
  size_t off = 0;
  auto carve = [&](size_t bytes) -> char* {
    off = (off + 255) & ~(size_t)255;
    char* p = ws + off; off += bytes; return p;
  };

  unsigned short* xcn   = (unsigned short*)carve((size_t)B_ * C_ * N_ * 2);  // reused as sT
  unsigned short* xnc   = (unsigned short*)carve((size_t)B_ * C_ * N_ * 2);
  unsigned short* wqkb  = (unsigned short*)carve(128 * 512 * 2);
  unsigned short* wvb   = (unsigned short*)carve(512 * 512 * 2);
  unsigned short* wfb   = (unsigned short*)carve(512 * 512 * 2);
  unsigned short* qkT   = (unsigned short*)carve((size_t)B_ * N_ * 128 * 2);
  unsigned short* vmat  = (unsigned short*)carve((size_t)B_ * C_ * N_ * 2);
  float*          cepart= (float*)carve((size_t)4 * B_ * 512 * 512 * 4);     // reused as yT (bf16)
  unsigned short* cattn = (unsigned short*)carve((size_t)B_ * 512 * 512 * 2);
  unsigned short* caT   = (unsigned short*)carve((size_t)B_ * N_ * C_ * 2);
  float*          bnpart= (float*)carve((size_t)128 * 1024 * 4);

  unsigned short* yT = (unsigned short*)cepart;  // overlay: cepart dead after ce_softmax
  unsigned short* sT = xcn;                      // overlay: xcn dead after ce GEMM

  // 1) conversions (x + weights in one launch)
  convert_x_k<<<dim3(C_ / 64, N_ / 64, 5), 256, 0, stream>>>(
      x, xcn, xnc, wq, wk, wv, wf, wqkb, wvb, wfb);

  // 2) merged independent GEMMs: ce (split-K, first), qkT, v — 896 blocks
  gemm3_k<<<dim3(896), 256, 0, stream>>>(xnc, xcn, wqkb, wvb, qkT, vmat, cepart);

  // 3) channel softmax -> cattn bf16
  ce_softmax_k<<<dim3(B_ * 512 / 4), 256, 0, stream>>>(cepart, cattn);

  // 4) caT[n][c] = xnc @ cattn^T
  gemm_bt<EPI_BF16><<<dim3(32, 4, 4), 256, 0, stream>>>(
      xnc, 512, (size_t)N_ * C_, cattn, 512, (size_t)512 * 512,
      caT, 512, (size_t)N_ * C_ * 2, 512, nullptr);

  // 5) fused position attention + combine epilogue -> sT
  fused_pa_k<<<dim3(256), 512, 0, stream>>>(qkT, vmat, caT, xnc, gpa, gca, sT);

  // 6) yT[n][o] = sT @ wfuse^T (bf16) with fused per-block BN column partials
  gemm_bt<EPI_YB><<<dim3(32, 4, 4), 256, 0, stream>>>(
      sT, 512, (size_t)N_ * C_, wfb, 512, 0,
      yT, 512, (size_t)N_ * C_ * 2, 512, bnpart);

  // 7) BN finalize (inline) + apply + transpose + relu
  bn_apply_k<<<dim3(N_ / 64, C_ / 64, B_), 256, 0, stream>>>(yT, bnpart, bns, bnb, out);
}